// Round 5
// baseline (1385.065 us; speedup 1.0000x reference)
//
#include <hip/hip_runtime.h>

// Neighbor search: M=N=12288, DIM=3.
// d_out layout (float32, flat, return order):
//   [0 .. M]                row_splits (M+1 counts-prefix as floats)
//   [M+1 .. M+1+M*N)        mask (0.0 / 1.0)
//   [M+1+M*N .. +2*M*N)     weights (d2 if mask else 0)
//
// R1-R4 post-mortem: four disjoint row-owned kernels all ~470us (2.5 TB/s
// effective) vs the harness fill's 6.2 TB/s on the same buffer; kernel is
// insensitive to instruction count / gathers / store width / phase. Last
// structural invariant: ~4096 concurrent private write streams -> HBM
// row-buffer thrash. R5: mimic the fill exactly -- grid-stride sweep of the
// flat [M*N] domain so the whole dispatch forms one dense contiguous write
// front (8 MB window sweeping), per-row q/data precomputed into L2-resident
// float4 tables, counts via rare conditional atomics (~0.26% in-radius).
//
// Numerics (unchanged since R1, absmax 256, threshold 7004):
//   sq = (x*x + y*y) + z*z               (each op rounded)
//   dot = fma(q2,d2, fma(q1,d1, q0*d0))  (sgemm ascending-k chain)
//   v = fma(-2, dot, sq_q+sq_d)          (== (sq_q+sq_d) - 2*dot exactly)
//   v = max(v,0); mask = v <= r*r

#define GRID_MAIN 2048  // 2048 blocks x 256 thr = 32 waves/CU, all resident

// Precompute {x,y,z,sq} tables for queries and data; zero counts.
__global__ __launch_bounds__(256) void pre_kernel(
    const float* __restrict__ data, const float* __restrict__ queries,
    int M, int N, int* __restrict__ counts,
    float4* __restrict__ qpre, float4* __restrict__ dpre)
{
    const int t = blockIdx.x * 256 + threadIdx.x;
    if (t < M) {
        const float q0 = queries[3 * t], q1 = queries[3 * t + 1], q2 = queries[3 * t + 2];
        const float sq = __fadd_rn(
            __fadd_rn(__fmul_rn(q0, q0), __fmul_rn(q1, q1)), __fmul_rn(q2, q2));
        qpre[t] = make_float4(q0, q1, q2, sq);
        counts[t] = 0;
    }
    if (t < N) {
        const float d0 = data[3 * t], d1 = data[3 * t + 1], d2 = data[3 * t + 2];
        const float sq = __fadd_rn(
            __fadd_rn(__fmul_rn(d0, d0), __fmul_rn(d1, d1)), __fmul_rn(d2, d2));
        dpre[t] = make_float4(d0, d1, d2, sq);
    }
}

// Grid-stride linear sweep over flat f in [0, M*N). Quad k covers
// f = 3+4k .. 6+4k so that out-index mask_off+f (== 12292+4k) is 16B
// aligned for float4 stores in BOTH output streams. Head {0,1,2} and tail
// {F-1} peeled by block 0. N is a template constant (magic-mul division).
template <int N>
__global__ __launch_bounds__(256) void sweep_kernel(
    const float* __restrict__ radius_p, float* __restrict__ out,
    int* __restrict__ counts,
    const float4* __restrict__ qpre, const float4* __restrict__ dpre,
    int M, long long mask_off, long long w_off)
{
    const float r = radius_p[0];
    const float r2 = __fmul_rn(r, r);
    const long long F = (long long)M * N;
    const int K = (int)((F - 4) >> 2);  // # quads

    auto comp = [&](const float4& q, const float4& d, float& mve, float& wve) -> int {
        const float dot = __fmaf_rn(q.z, d.z, __fmaf_rn(q.y, d.y, __fmul_rn(q.x, d.x)));
        float v = __fmaf_rn(-2.0f, dot, __fadd_rn(q.w, d.w));
        v = fmaxf(v, 0.0f);
        const bool in = (v <= r2);
        mve = in ? 1.0f : 0.0f;
        wve = in ? v : 0.0f;
        return in ? 1 : 0;
    };

    // Peel: f in {0,1,2,F-1}.
    if (blockIdx.x == 0 && threadIdx.x < 4) {
        const long long f = (threadIdx.x < 3) ? (long long)threadIdx.x : (F - 1);
        const int m = (int)(f / N);
        const int n = (int)(f - (long long)m * N);
        float mv, wv;
        const int c = comp(qpre[m], dpre[n], mv, wv);
        out[mask_off + f] = mv;
        out[w_off + f] = wv;
        if (c) atomicAdd(&counts[m], 1);
    }

    const int stride = gridDim.x * 256;
    for (int k = blockIdx.x * 256 + threadIdx.x; k < K; k += stride) {
        const int f0 = 3 + 4 * k;
        const int m = f0 / N;  // constexpr N -> magic multiply
        const int n0 = f0 - m * N;
        float4 mv, wv;
        if (n0 <= N - 4) {  // whole quad in one row (usual case)
            const float4 q = qpre[m];  // wave-uniform -> L1 broadcast
            const float4 da = dpre[n0 + 0];  // lanes read 64B each, wave 4KB dense
            const float4 db = dpre[n0 + 1];
            const float4 dc = dpre[n0 + 2];
            const float4 dd = dpre[n0 + 3];
            int c = comp(q, da, mv.x, wv.x);
            c += comp(q, db, mv.y, wv.y);
            c += comp(q, dc, mv.z, wv.z);
            c += comp(q, dd, mv.w, wv.w);
            if (c) atomicAdd(&counts[m], c);  // ~1% of quads
        } else {  // quad straddles a row boundary (1 in 3072)
            #pragma unroll
            for (int e = 0; e < 4; ++e) {
                const int fe = f0 + e;
                const int me = fe / N;
                const int ne = fe - me * N;
                float mve, wve;
                const int c = comp(qpre[me], dpre[ne], mve, wve);
                reinterpret_cast<float*>(&mv)[e] = mve;
                reinterpret_cast<float*>(&wv)[e] = wve;
                if (c) atomicAdd(&counts[me], 1);
            }
        }
        // Both streams: dense contiguous front across the whole grid.
        *reinterpret_cast<float4*>(out + mask_off + f0) = mv;
        *reinterpret_cast<float4*>(out + w_off + f0) = wv;
    }
}

// Generic fallback (shape assumptions not met): row-owned, correct-first.
__global__ __launch_bounds__(256) void nbr_kernel_generic(
    const float* __restrict__ data,
    const float* __restrict__ queries,
    const float* __restrict__ radius_p,
    float* __restrict__ out,
    int* __restrict__ counts,
    int N, long long mask_off, long long w_off)
{
    const int m = blockIdx.x;
    const int tid = threadIdx.x;
    const float r = radius_p[0];
    const float r2 = __fmul_rn(r, r);
    const float q0 = queries[3 * m], q1 = queries[3 * m + 1], q2 = queries[3 * m + 2];
    const float sq_q = __fadd_rn(
        __fadd_rn(__fmul_rn(q0, q0), __fmul_rn(q1, q1)), __fmul_rn(q2, q2));
    float* mask_row = out + mask_off + (long long)m * N;
    float* w_row    = out + w_off    + (long long)m * N;
    int cnt = 0;
    for (int n = tid; n < N; n += 256) {
        const float d0 = data[3 * n], d1 = data[3 * n + 1], d2e = data[3 * n + 2];
        const float sq_d = __fadd_rn(
            __fadd_rn(__fmul_rn(d0, d0), __fmul_rn(d1, d1)), __fmul_rn(d2e, d2e));
        const float dot = __fmaf_rn(q2, d2e, __fmaf_rn(q1, d1, __fmul_rn(q0, d0)));
        float v = __fmaf_rn(-2.0f, dot, __fadd_rn(sq_q, sq_d));
        v = fmaxf(v, 0.0f);
        const bool in = (v <= r2);
        mask_row[n] = in ? 1.0f : 0.0f;
        w_row[n] = in ? v : 0.0f;
        cnt += in ? 1 : 0;
    }
    for (int off = 32; off > 0; off >>= 1) cnt += __shfl_down(cnt, off);
    __shared__ int lds_cnt;
    if (tid == 0) lds_cnt = 0;
    __syncthreads();
    if ((tid & 63) == 0) atomicAdd(&lds_cnt, cnt);
    __syncthreads();
    if (tid == 0) counts[m] = lds_cnt;
}

// Single-block exclusive scan of counts[M] -> row_splits[M+1] (as floats).
__global__ __launch_bounds__(256) void scan_kernel(
    const int* __restrict__ counts, float* __restrict__ out, int M)
{
    __shared__ int sums[256];
    const int t = threadIdx.x;
    const int CH = (M + 255) / 256;  // 48 for M=12288
    const int base = t * CH;

    int local[64];  // CH <= 64 assumed
    int s = 0;
    for (int i = 0; i < CH; ++i) {
        const int v = (base + i < M) ? counts[base + i] : 0;
        local[i] = v;
        s += v;
    }
    sums[t] = s;
    __syncthreads();
    for (int off = 1; off < 256; off <<= 1) {
        const int v = (t >= off) ? sums[t - off] : 0;
        __syncthreads();
        sums[t] += v;
        __syncthreads();
    }
    int prefix = sums[t] - s;  // exclusive prefix of this thread's chunk
    for (int i = 0; i < CH; ++i) {
        if (base + i < M) out[base + i] = (float)prefix;
        prefix += local[i];
    }
    if (t == 255) out[M] = (float)prefix;  // total
}

extern "C" void kernel_launch(void* const* d_in, const int* in_sizes, int n_in,
                              void* d_out, int out_size, void* d_ws, size_t ws_size,
                              hipStream_t stream) {
    const float* data    = (const float*)d_in[0];
    const float* queries = (const float*)d_in[1];
    const float* radius  = (const float*)d_in[2];

    const int N = in_sizes[0] / 3;  // 12288
    const int M = in_sizes[1] / 3;  // 12288

    float* out = (float*)d_out;

    // d_ws layout: counts int[M] | qpre float4[M] (16B-aligned) | dpre float4[N]
    int* counts = (int*)d_ws;
    const size_t cnt_bytes = ((size_t)M * sizeof(int) + 15) & ~(size_t)15;
    float4* qpre = (float4*)((char*)d_ws + cnt_bytes);
    float4* dpre = qpre + M;

    const long long mask_off = (long long)M + 1;
    const long long w_off = mask_off + (long long)M * N;

    const size_t ws_need = cnt_bytes + (size_t)(M + N) * sizeof(float4);
    if (N == 12288 && M == 12288 && ws_size >= ws_need) {
        const int pre_blocks = (max(M, N) + 255) / 256;
        pre_kernel<<<pre_blocks, 256, 0, stream>>>(data, queries, M, N,
                                                   counts, qpre, dpre);
        sweep_kernel<12288><<<GRID_MAIN, 256, 0, stream>>>(
            radius, out, counts, qpre, dpre, M, mask_off, w_off);
    } else {
        nbr_kernel_generic<<<M, 256, 0, stream>>>(data, queries, radius, out,
                                                  counts, N, mask_off, w_off);
    }
    scan_kernel<<<1, 256, 0, stream>>>(counts, out, M);
}